// Round 1
// baseline (305.085 us; speedup 1.0000x reference)
//
#include <hip/hip_runtime.h>

// B=512, P=64, K=8, D=512, T=50000
// out: [B*P, 2*D] fp32
#define BB 512
#define PP 64
#define KK 8
#define DD 512

typedef float v4f __attribute__((ext_vector_type(4)));

// ---------------------------------------------------------------------------
// Two-phase split: the neighbor-job gather stream (inputs table, 64 MB) and
// the title gather stream (title table, 102 MB) each fit in the 256 MB L3 on
// their own, but not comfortably together with the write stream. Separating
// them temporally (two launches) makes each phase's gathers L3-resident ->
// near-compulsory HBM fetch (~170 MB vs measured 289 MB fused).
// ---------------------------------------------------------------------------

// Phase 1: attention logits + masked softmax. One wave per (b,p) row.
// Writes sim weights [B*P, K] to workspace and the focal half of out.
__global__ __launch_bounds__(256) void han_phase1(
    const float* __restrict__ inputs,       // [B,P,D]
    const int*   __restrict__ nbr_batch,    // [B,P,K]
    const int*   __restrict__ nbr_job,      // [B,P,K]
    const int*   __restrict__ nbr_mask,     // [B,P,K]
    float*       __restrict__ out,          // [B*P, 2*D]
    float*       __restrict__ sim)          // [B*P, K] workspace
{
    const int lane = threadIdx.x & 63;
    const int wave = threadIdx.x >> 6;
    const int row  = blockIdx.x * 4 + wave;        // in [0, B*P)

    // focal embedding: each lane owns d=lane*4..+3 and d=256+lane*4..+3
    const float4* inp4 = (const float4*)(inputs + (size_t)row * DD);
    const float4 fa = inp4[lane];
    const float4 fb = inp4[lane + 64];

    const int4* nb4 = (const int4*)(nbr_batch + row * KK);
    const int4* nj4 = (const int4*)(nbr_job   + row * KK);
    const int4* nm4 = (const int4*)(nbr_mask  + row * KK);
    int nbk[KK], njk[KK], nmk[KK];
    *(int4*)&nbk[0] = nb4[0]; *(int4*)&nbk[4] = nb4[1];
    *(int4*)&njk[0] = nj4[0]; *(int4*)&njk[4] = nj4[1];
    *(int4*)&nmk[0] = nm4[0]; *(int4*)&nmk[4] = nm4[1];

    // logits: dot(focal, neighbor) for unmasked k (mask is wave-uniform)
    float logit[KK];
    #pragma unroll
    for (int k = 0; k < KK; ++k) {
        if (nmk[k]) {
            const float4* g4 = (const float4*)(inputs +
                ((size_t)nbk[k] * PP + (size_t)njk[k]) * DD);
            const float4 ga = g4[lane];
            const float4 gb = g4[lane + 64];
            float d = fa.x*ga.x + fa.y*ga.y + fa.z*ga.z + fa.w*ga.w
                    + fb.x*gb.x + fb.y*gb.y + fb.z*gb.z + fb.w*gb.w;
            #pragma unroll
            for (int off = 32; off >= 1; off >>= 1)
                d += __shfl_xor(d, off, 64);
            logit[k] = d;
        } else {
            logit[k] = -1e9f;
        }
    }

    // masked softmax over K=8 (replicated per lane; all scalar)
    float m = logit[0];
    #pragma unroll
    for (int k = 1; k < KK; ++k) m = fmaxf(m, logit[k]);
    float e[KK];
    float s = 0.0f;
    #pragma unroll
    for (int k = 0; k < KK; ++k) {
        e[k] = expf(logit[k] - m);
        s += e[k];
    }
    const float inv = 1.0f / s;

    // focal half of out: write-once -> non-temporal
    v4f* o4 = (v4f*)(out + (size_t)row * (2 * DD));
    v4f va = {fa.x, fa.y, fa.z, fa.w};
    v4f vb = {fb.x, fb.y, fb.z, fb.w};
    __builtin_nontemporal_store(va, o4 + lane);        // d 0..255
    __builtin_nontemporal_store(vb, o4 + lane + 64);   // d 256..511

    // sim weights: exact 0 on masked slots (phase 2 uses w!=0 to skip the
    // gather). 32 B per row, written by lane 0, regular store (re-read soon).
    if (lane == 0) {
        float4* s4 = (float4*)(sim + (size_t)row * KK);
        s4[0] = make_float4(nmk[0] ? e[0]*inv : 0.f,
                            nmk[1] ? e[1]*inv : 0.f,
                            nmk[2] ? e[2]*inv : 0.f,
                            nmk[3] ? e[3]*inv : 0.f);
        s4[1] = make_float4(nmk[4] ? e[4]*inv : 0.f,
                            nmk[5] ? e[5]*inv : 0.f,
                            nmk[6] ? e[6]*inv : 0.f,
                            nmk[7] ? e[7]*inv : 0.f);
    }
}

// Phase 2: weighted sum of title embeddings. One wave per (b,p) row.
// Only touches the title table -> it stays L3-resident by itself.
__global__ __launch_bounds__(256) void han_phase2(
    const float* __restrict__ title,        // [T,D]
    const int*   __restrict__ nbr_title,    // [B,P,K]
    const float* __restrict__ sim,          // [B*P, K]
    float*       __restrict__ out)          // [B*P, 2*D]
{
    const int lane = threadIdx.x & 63;
    const int wave = threadIdx.x >> 6;
    const int row  = blockIdx.x * 4 + wave;

    const int4* nt4 = (const int4*)(nbr_title + row * KK);
    int ntk[KK];
    *(int4*)&ntk[0] = nt4[0]; *(int4*)&ntk[4] = nt4[1];

    // wave-uniform weights (broadcast via L1); fully unrolled -> registers
    const float4* s4 = (const float4*)(sim + (size_t)row * KK);
    const float4 w0 = s4[0];
    const float4 w1 = s4[1];
    const float w[KK] = {w0.x, w0.y, w0.z, w0.w, w1.x, w1.y, w1.z, w1.w};

    float4 oa = make_float4(0.f, 0.f, 0.f, 0.f);
    float4 ob = make_float4(0.f, 0.f, 0.f, 0.f);
    #pragma unroll
    for (int k = 0; k < KK; ++k) {
        if (w[k] != 0.0f) {   // masked slots are exact 0 -> skip the 2 KB gather
            const float4* t4 = (const float4*)(title + (size_t)ntk[k] * DD);
            const float4 ta = t4[lane];
            const float4 tb = t4[lane + 64];
            oa.x += w[k]*ta.x; oa.y += w[k]*ta.y; oa.z += w[k]*ta.z; oa.w += w[k]*ta.w;
            ob.x += w[k]*tb.x; ob.y += w[k]*tb.y; ob.z += w[k]*tb.z; ob.w += w[k]*tb.w;
        }
    }

    v4f* o4 = (v4f*)(out + (size_t)row * (2 * DD));
    v4f vc = {oa.x, oa.y, oa.z, oa.w};
    v4f vd = {ob.x, ob.y, ob.z, ob.w};
    __builtin_nontemporal_store(vc, o4 + lane + 128);  // graph 0..255
    __builtin_nontemporal_store(vd, o4 + lane + 192);  // graph 256..511
}

// ---------------------------------------------------------------------------
// Fallback: original fused kernel (used only if workspace is too small).
// ---------------------------------------------------------------------------
__global__ __launch_bounds__(256) void han_meta_kernel(
    const float* __restrict__ inputs,
    const float* __restrict__ title,
    const int*   __restrict__ nbr_batch,
    const int*   __restrict__ nbr_job,
    const int*   __restrict__ nbr_title,
    const int*   __restrict__ nbr_mask,
    float*       __restrict__ out)
{
    const int lane = threadIdx.x & 63;
    const int wave = threadIdx.x >> 6;
    const int row  = blockIdx.x * 4 + wave;

    const float4* inp4 = (const float4*)(inputs + (size_t)row * DD);
    const float4 fa = inp4[lane];
    const float4 fb = inp4[lane + 64];

    const int4* nb4 = (const int4*)(nbr_batch + row * KK);
    const int4* nj4 = (const int4*)(nbr_job   + row * KK);
    const int4* nt4 = (const int4*)(nbr_title + row * KK);
    const int4* nm4 = (const int4*)(nbr_mask  + row * KK);
    int nbk[KK], njk[KK], ntk[KK], nmk[KK];
    *(int4*)&nbk[0] = nb4[0]; *(int4*)&nbk[4] = nb4[1];
    *(int4*)&njk[0] = nj4[0]; *(int4*)&njk[4] = nj4[1];
    *(int4*)&ntk[0] = nt4[0]; *(int4*)&ntk[4] = nt4[1];
    *(int4*)&nmk[0] = nm4[0]; *(int4*)&nmk[4] = nm4[1];

    float logit[KK];
    #pragma unroll
    for (int k = 0; k < KK; ++k) {
        if (nmk[k]) {
            const float4* g4 = (const float4*)(inputs +
                ((size_t)nbk[k] * PP + (size_t)njk[k]) * DD);
            const float4 ga = g4[lane];
            const float4 gb = g4[lane + 64];
            float d = fa.x*ga.x + fa.y*ga.y + fa.z*ga.z + fa.w*ga.w
                    + fb.x*gb.x + fb.y*gb.y + fb.z*gb.z + fb.w*gb.w;
            #pragma unroll
            for (int off = 32; off >= 1; off >>= 1)
                d += __shfl_xor(d, off, 64);
            logit[k] = d;
        } else {
            logit[k] = -1e9f;
        }
    }

    float m = logit[0];
    #pragma unroll
    for (int k = 1; k < KK; ++k) m = fmaxf(m, logit[k]);
    float e[KK];
    float s = 0.0f;
    #pragma unroll
    for (int k = 0; k < KK; ++k) {
        e[k] = expf(logit[k] - m);
        s += e[k];
    }
    const float inv = 1.0f / s;

    float4 oa = make_float4(0.f, 0.f, 0.f, 0.f);
    float4 ob = make_float4(0.f, 0.f, 0.f, 0.f);
    #pragma unroll
    for (int k = 0; k < KK; ++k) {
        if (nmk[k]) {
            const float w = e[k] * inv;
            const float4* t4 = (const float4*)(title + (size_t)ntk[k] * DD);
            const float4 ta = t4[lane];
            const float4 tb = t4[lane + 64];
            oa.x += w * ta.x; oa.y += w * ta.y; oa.z += w * ta.z; oa.w += w * ta.w;
            ob.x += w * tb.x; ob.y += w * tb.y; ob.z += w * tb.z; ob.w += w * tb.w;
        }
    }

    v4f* o4 = (v4f*)(out + (size_t)row * (2 * DD));
    v4f va = {fa.x, fa.y, fa.z, fa.w};
    v4f vb = {fb.x, fb.y, fb.z, fb.w};
    v4f vc = {oa.x, oa.y, oa.z, oa.w};
    v4f vd = {ob.x, ob.y, ob.z, ob.w};
    __builtin_nontemporal_store(va, o4 + lane);
    __builtin_nontemporal_store(vb, o4 + lane + 64);
    __builtin_nontemporal_store(vc, o4 + lane + 128);
    __builtin_nontemporal_store(vd, o4 + lane + 192);
}

extern "C" void kernel_launch(void* const* d_in, const int* in_sizes, int n_in,
                              void* d_out, int out_size, void* d_ws, size_t ws_size,
                              hipStream_t stream) {
    const float* inputs    = (const float*)d_in[0];
    const float* title     = (const float*)d_in[1];
    const int*   nbr_batch = (const int*)d_in[2];
    const int*   nbr_job   = (const int*)d_in[3];
    const int*   nbr_title = (const int*)d_in[4];
    const int*   nbr_mask  = (const int*)d_in[5];
    float*       out       = (float*)d_out;

    const int rows = BB * PP;                 // 32768
    const size_t sim_bytes = (size_t)rows * KK * sizeof(float);  // 1 MB

    dim3 grid(rows / 4);   // 4 waves (rows) per 256-thread block
    dim3 block(256);

    if (ws_size >= sim_bytes) {
        float* sim = (float*)d_ws;
        han_phase1<<<grid, block, 0, stream>>>(
            inputs, nbr_batch, nbr_job, nbr_mask, out, sim);
        han_phase2<<<grid, block, 0, stream>>>(
            title, nbr_title, sim, out);
    } else {
        han_meta_kernel<<<grid, block, 0, stream>>>(
            inputs, title, nbr_batch, nbr_job, nbr_title, nbr_mask, out);
    }
}